// Round 3
// baseline (292.922 us; speedup 1.0000x reference)
//
#include <hip/hip_runtime.h>
#include <stdint.h>

// Problem: B=32, W=16, N=256, DIM=256, GAMMA=4, V=64, TABLE=961
// out[b,w,m,vv*4+s] = sum_nn bias_table[rel_index[m,nn], s*16+w] * x[b,w,nn,vv*4+s]
//                     + token_bias[w*4+s, m]
// I/O dtype resolved AT RUNTIME (fp32 vs bf16) via exponent-field sniff of x;
// compute path: bf16 MFMA with fp32 accumulation either way.

typedef __attribute__((ext_vector_type(8))) short bf16x8;
typedef __attribute__((ext_vector_type(4))) float f32x4;
typedef __attribute__((ext_vector_type(8))) unsigned short u16x8;

__device__ __forceinline__ unsigned short f2bf(float f) {
    union { float f; unsigned u; } v; v.f = f;
    unsigned u = v.u;
    u += 0x7FFFu + ((u >> 16) & 1u);          // round-nearest-even
    return (unsigned short)(u >> 16);
}
__device__ __forceinline__ float bf2f(unsigned short h) {
    union { unsigned u; float f; } v; v.u = ((unsigned)h) << 16;
    return v.f;
}
// 1 if this u16, viewed as bf16, has a plausible N(0,1)-ish exponent.
// bf16 buffer: ~99% of words qualify. fp32 buffer: low-mantissa halves are
// uniform-random -> ~16% qualify.
__device__ __forceinline__ int expInRange(unsigned short w16) {
    int e = (w16 >> 7) & 0xFF;
    return (e >= 100 && e <= 140) ? 1 : 0;
}

// ---------- Pass 1: gather Ab[plane=w*4+s][m][nn] as bf16 into d_ws (8 MB) ----------
__global__ __launch_bounds__(256) void k_gather(
    const void* __restrict__ bt_raw,                 // bias_table (961,64) fp32|bf16
    const int*  __restrict__ rel_index,              // (256,256) int32
    const void* __restrict__ x_raw,                  // only for dtype sniff
    unsigned short* __restrict__ Ab)                 // (64,256,256) bf16
{
    const unsigned short* xw = (const unsigned short*)x_raw;
    int t = threadIdx.x;
    int pred = expInRange(xw[t * 2]) & expInRange(xw[t * 2 + 1]);
    int cnt = __syncthreads_count(pred);             // bf16 ~251, fp32 ~41
    bool isF32 = (cnt < 150);

    int idx4 = blockIdx.x * 256 + t;
    int base = idx4 << 2;                            // element index in Ab
    int nn = base & 255;
    int m  = (base >> 8) & 255;
    int ws = base >> 16;                             // plane = w*4 + s
    int colw = ((ws & 3) << 4) + (ws >> 2);          // s*16 + w
    const int* ri = rel_index + (m << 8) + nn;
    int i0 = ri[0], i1 = ri[1], i2 = ri[2], i3 = ri[3];
    ushort4 o;
    if (isF32) {
        const float* bt = (const float*)bt_raw;
        o.x = f2bf(bt[(i0 << 6) + colw]);
        o.y = f2bf(bt[(i1 << 6) + colw]);
        o.z = f2bf(bt[(i2 << 6) + colw]);
        o.w = f2bf(bt[(i3 << 6) + colw]);
    } else {
        const unsigned short* bt = (const unsigned short*)bt_raw;
        o.x = bt[(i0 << 6) + colw];
        o.y = bt[(i1 << 6) + colw];
        o.z = bt[(i2 << 6) + colw];
        o.w = bt[(i3 << 6) + colw];
    }
    *(ushort4*)(Ab + base) = o;
}

// ---------- Pass 2: MFMA GEMM ----------
// grid: bx = (w*2 + mt)*32 + b (1024 blocks), block 512 threads (8 waves)
// wave = (s = wave&3, vv-half = wave>>2); per-wave tile m 128 x vv 32, K=256
// LDS (elements): As [s4][m128][nn32] @0, Xs [s4][vv64][nn32] @16384
__global__ __launch_bounds__(512, 4) void k_main(
    const void* __restrict__ x_raw,                  // (32,16,256,256) fp32|bf16
    const unsigned short* __restrict__ Ab,           // (64,256,256) bf16
    const void* __restrict__ tb_raw,                 // (64,256) fp32|bf16
    void* __restrict__ out_raw)                      // (32,16,256,256) fp32|bf16
{
    __shared__ unsigned short lds[16384 + 8192];

    const int tid  = threadIdx.x;
    const unsigned short* xw = (const unsigned short*)x_raw;
    int pred = expInRange(xw[tid]);
    int cnt = __syncthreads_count(pred);             // bf16 ~506, fp32 ~295
    const bool isF32 = (cnt < 400);

    const int lane = tid & 63;
    const int wave = tid >> 6;
    const int bx = blockIdx.x;
    const int b  = bx & 31;
    const int mt = (bx >> 5) & 1;
    const int w  = bx >> 6;
    const int m0 = mt << 7;

    const int sw   = wave & 3;
    const int vh   = wave >> 2;
    const int vvb  = vh << 5;
    const int col  = lane & 15;
    const int quad = lane >> 4;

    // A staging: thread t covers row a_row, cols a_nn8..+8 of 4 planes
    const int a_row = tid >> 2;                      // 0..127
    const int a_nn8 = (tid & 3) << 3;                // 0,8,16,24
    unsigned short* AsW = lds + (a_row << 5) + a_nn8;
    const unsigned short* Ag = Ab + (w << 18) + ((m0 + a_row) << 8) + a_nn8;

    // X staging: thread t: nn = t&31, vg = t>>5 (16 d-values each)
    const int x_nn = tid & 31;
    const int x_vg = tid >> 5;
    const int xoff = (((b << 4) + w) << 16) + (x_nn << 8) + (x_vg << 4);
    const float*          Xgf = (const float*)x_raw + xoff;
    const unsigned short* Xgh = (const unsigned short*)x_raw + xoff;
    unsigned short* XsW = lds + 16384 + x_nn;

    f32x4 acc[8][2];
#pragma unroll
    for (int mi = 0; mi < 8; mi++) {
        acc[mi][0] = (f32x4){0.f, 0.f, 0.f, 0.f};
        acc[mi][1] = (f32x4){0.f, 0.f, 0.f, 0.f};
    }

    const unsigned short* AsR = lds + (sw << 12) + (col << 5) + (quad << 3);
    const unsigned short* XsR = lds + 16384 + (sw << 11) + ((vvb + col) << 5) + (quad << 3);

    for (int nc = 0; nc < 8; nc++) {
        // ---- A tile: 4 planes x 128 m x 32 nn (bf16 from Ab)
        u16x8 av[4];
#pragma unroll
        for (int it = 0; it < 4; it++)
            av[it] = *(const u16x8*)(Ag + (it << 16) + (nc << 5));
#pragma unroll
        for (int it = 0; it < 4; it++)
            *(u16x8*)(AsW + (it << 12)) = av[it];

        // ---- X tile: nn = nc*32 + x_nn, d = x_vg*16 + j -> Xs[s][vv][nn]
        if (isF32) {
            float4 v[4];
#pragma unroll
            for (int i = 0; i < 4; i++)
                v[i] = *(const float4*)(Xgf + (nc << 13) + (i << 2));
            const float* vf = (const float*)v;
#pragma unroll
            for (int j = 0; j < 16; j++) {
                int vv = (x_vg << 2) + (j >> 2);
                XsW[((j & 3) << 11) + (vv << 5)] = f2bf(vf[j]);
            }
        } else {
            u16x8 xv0 = *(const u16x8*)(Xgh + (nc << 13));
            u16x8 xv1 = *(const u16x8*)(Xgh + (nc << 13) + 8);
#pragma unroll
            for (int j = 0; j < 8; j++) {
                int vv = (x_vg << 2) + (j >> 2);
                XsW[((j & 3) << 11) + (vv << 5)] = xv0[j];
            }
#pragma unroll
            for (int j = 0; j < 8; j++) {
                int vv = (x_vg << 2) + 2 + (j >> 2);
                XsW[((j & 3) << 11) + (vv << 5)] = xv1[j];
            }
        }
        __syncthreads();

        bf16x8 bfr0 = *(const bf16x8*)(XsR);
        bf16x8 bfr1 = *(const bf16x8*)(XsR + 512);
#pragma unroll
        for (int mi = 0; mi < 8; mi++) {
            bf16x8 afr = *(const bf16x8*)(AsR + (mi << 9));
            acc[mi][0] = __builtin_amdgcn_mfma_f32_16x16x32_bf16(afr, bfr0, acc[mi][0], 0, 0, 0);
            acc[mi][1] = __builtin_amdgcn_mfma_f32_16x16x32_bf16(afr, bfr1, acc[mi][1], 0, 0, 0);
        }
        __syncthreads();
    }

    // ---- epilogue: D[row=m=quad*4+r][col=vv], + token_bias[w*4+s, m]
    const int tboff = (((w << 2) + sw) << 8) + m0;
    const int ooff  = (((b << 4) + w) << 16) + (m0 << 8) + sw;
    if (isF32) {
        const float* tb = (const float*)tb_raw + tboff;
        float* ob = (float*)out_raw + ooff;
#pragma unroll
        for (int mi = 0; mi < 8; mi++) {
#pragma unroll
            for (int r = 0; r < 4; r++) {
                int m = (mi << 4) + (quad << 2) + r;
                float bias = tb[m];
#pragma unroll
                for (int vi = 0; vi < 2; vi++) {
                    int vv = vvb + (vi << 4) + col;
                    ob[(m << 8) + (vv << 2)] = acc[mi][vi][r] + bias;
                }
            }
        }
    } else {
        const unsigned short* tb = (const unsigned short*)tb_raw + tboff;
        unsigned short* ob = (unsigned short*)out_raw + ooff;
#pragma unroll
        for (int mi = 0; mi < 8; mi++) {
#pragma unroll
            for (int r = 0; r < 4; r++) {
                int m = (mi << 4) + (quad << 2) + r;
                float bias = bf2f(tb[m]);
#pragma unroll
                for (int vi = 0; vi < 2; vi++) {
                    int vv = vvb + (vi << 4) + col;
                    ob[(m << 8) + (vv << 2)] = f2bf(acc[mi][vi][r] + bias);
                }
            }
        }
    }
}

// ---------- Fallback (ws too small): in-loop gather, dual-dtype ----------
__global__ __launch_bounds__(512, 4) void k_main_fused(
    const void* __restrict__ x_raw,
    const void* __restrict__ bt_raw,
    const int*  __restrict__ rel_index,
    const void* __restrict__ tb_raw,
    void* __restrict__ out_raw)
{
    __shared__ unsigned short lds[16384 + 8192];

    const int tid  = threadIdx.x;
    const unsigned short* xw = (const unsigned short*)x_raw;
    int pred = expInRange(xw[tid]);
    int cnt = __syncthreads_count(pred);
    const bool isF32 = (cnt < 400);

    const int lane = tid & 63;
    const int wave = tid >> 6;
    const int bx = blockIdx.x;
    const int b  = bx & 31;
    const int mt = (bx >> 5) & 1;
    const int w  = bx >> 6;
    const int m0 = mt << 7;

    const int sw   = wave & 3;
    const int vh   = wave >> 2;
    const int vvb  = vh << 5;
    const int col  = lane & 15;
    const int quad = lane >> 4;

    const int a_row = tid >> 2;
    const int a_nn8 = (tid & 3) << 3;
    unsigned short* AsW = lds + (a_row << 5) + a_nn8;
    const int* rIp = rel_index + ((m0 + a_row) << 8) + a_nn8;

    const int x_nn = tid & 31;
    const int x_vg = tid >> 5;
    const int xoff = (((b << 4) + w) << 16) + (x_nn << 8) + (x_vg << 4);
    const float*          Xgf = (const float*)x_raw + xoff;
    const unsigned short* Xgh = (const unsigned short*)x_raw + xoff;
    unsigned short* XsW = lds + 16384 + x_nn;

    f32x4 acc[8][2];
#pragma unroll
    for (int mi = 0; mi < 8; mi++) {
        acc[mi][0] = (f32x4){0.f, 0.f, 0.f, 0.f};
        acc[mi][1] = (f32x4){0.f, 0.f, 0.f, 0.f};
    }

    const unsigned short* AsR = lds + (sw << 12) + (col << 5) + (quad << 3);
    const unsigned short* XsR = lds + 16384 + (sw << 11) + ((vvb + col) << 5) + (quad << 3);

    for (int nc = 0; nc < 8; nc++) {
        int4 r0 = *(const int4*)(rIp + (nc << 5));
        int4 r1 = *(const int4*)(rIp + (nc << 5) + 4);
        int ri[8] = {r0.x, r0.y, r0.z, r0.w, r1.x, r1.y, r1.z, r1.w};
#pragma unroll
        for (int it = 0; it < 4; it++) {
            u16x8 av;
            if (isF32) {
                const float* bt = (const float*)bt_raw;
#pragma unroll
                for (int j = 0; j < 8; j++)
                    av[j] = f2bf(bt[(ri[j] << 6) + (it << 4) + w]);
            } else {
                const unsigned short* bt = (const unsigned short*)bt_raw;
#pragma unroll
                for (int j = 0; j < 8; j++)
                    av[j] = bt[(ri[j] << 6) + (it << 4) + w];
            }
            *(u16x8*)(AsW + (it << 12)) = av;
        }

        if (isF32) {
            float4 v[4];
#pragma unroll
            for (int i = 0; i < 4; i++)
                v[i] = *(const float4*)(Xgf + (nc << 13) + (i << 2));
            const float* vf = (const float*)v;
#pragma unroll
            for (int j = 0; j < 16; j++) {
                int vv = (x_vg << 2) + (j >> 2);
                XsW[((j & 3) << 11) + (vv << 5)] = f2bf(vf[j]);
            }
        } else {
            u16x8 xv0 = *(const u16x8*)(Xgh + (nc << 13));
            u16x8 xv1 = *(const u16x8*)(Xgh + (nc << 13) + 8);
#pragma unroll
            for (int j = 0; j < 8; j++) {
                int vv = (x_vg << 2) + (j >> 2);
                XsW[((j & 3) << 11) + (vv << 5)] = xv0[j];
            }
#pragma unroll
            for (int j = 0; j < 8; j++) {
                int vv = (x_vg << 2) + 2 + (j >> 2);
                XsW[((j & 3) << 11) + (vv << 5)] = xv1[j];
            }
        }
        __syncthreads();

        bf16x8 bfr0 = *(const bf16x8*)(XsR);
        bf16x8 bfr1 = *(const bf16x8*)(XsR + 512);
#pragma unroll
        for (int mi = 0; mi < 8; mi++) {
            bf16x8 afr = *(const bf16x8*)(AsR + (mi << 9));
            acc[mi][0] = __builtin_amdgcn_mfma_f32_16x16x32_bf16(afr, bfr0, acc[mi][0], 0, 0, 0);
            acc[mi][1] = __builtin_amdgcn_mfma_f32_16x16x32_bf16(afr, bfr1, acc[mi][1], 0, 0, 0);
        }
        __syncthreads();
    }

    const int tboff = (((w << 2) + sw) << 8) + m0;
    const int ooff  = (((b << 4) + w) << 16) + (m0 << 8) + sw;
    if (isF32) {
        const float* tb = (const float*)tb_raw + tboff;
        float* ob = (float*)out_raw + ooff;
#pragma unroll
        for (int mi = 0; mi < 8; mi++) {
#pragma unroll
            for (int r = 0; r < 4; r++) {
                int m = (mi << 4) + (quad << 2) + r;
                float bias = tb[m];
#pragma unroll
                for (int vi = 0; vi < 2; vi++) {
                    int vv = vvb + (vi << 4) + col;
                    ob[(m << 8) + (vv << 2)] = acc[mi][vi][r] + bias;
                }
            }
        }
    } else {
        const unsigned short* tb = (const unsigned short*)tb_raw + tboff;
        unsigned short* ob = (unsigned short*)out_raw + ooff;
#pragma unroll
        for (int mi = 0; mi < 8; mi++) {
#pragma unroll
            for (int r = 0; r < 4; r++) {
                int m = (mi << 4) + (quad << 2) + r;
                float bias = bf2f(tb[m]);
#pragma unroll
                for (int vi = 0; vi < 2; vi++) {
                    int vv = vvb + (vi << 4) + col;
                    ob[(m << 8) + (vv << 2)] = f2bf(acc[mi][vi][r] + bias);
                }
            }
        }
    }
}

extern "C" void kernel_launch(void* const* d_in, const int* in_sizes, int n_in,
                              void* d_out, int out_size, void* d_ws, size_t ws_size,
                              hipStream_t stream) {
    const void* x          = d_in[0];
    const void* bias_table = d_in[1];
    const void* token_bias = d_in[2];
    const int*  rel_index  = (const int*)d_in[3];

    const size_t AB_BYTES = (size_t)64 * 256 * 256 * 2;   // 8 MB (bf16 Ab)
    if (ws_size >= AB_BYTES) {
        unsigned short* Ab = (unsigned short*)d_ws;
        hipLaunchKernelGGL(k_gather, dim3(4096), dim3(256), 0, stream,
                           bias_table, rel_index, x, Ab);
        hipLaunchKernelGGL(k_main, dim3(1024), dim3(512), 0, stream,
                           x, Ab, token_bias, d_out);
    } else {
        hipLaunchKernelGGL(k_main_fused, dim3(1024), dim3(512), 0, stream,
                           x, bias_table, rel_index, token_bias, d_out);
    }
}